// Round 6
// baseline (556.715 us; speedup 1.0000x reference)
//
#include <hip/hip_runtime.h>
#include <hip/hip_cooperative_groups.h>
#include <math.h>

namespace cg = cooperative_groups;

#define HID   1024
#define OUTD  8192
#define NSUBJ 8
#define BATCH 64
#define TLEN  512

// ws layout (float offsets)
#define OFF_PP    0u           // pool partials: 16*64*1024 = 1048576
#define OFF_P1    1048576u     // mlp1 partials: 16*64*1024
#define OFF_P2    2097152u     // mlp2 partials: 16*64*1024
#define OFF_H     3145728u     // 64*1024
#define OFF_MUP   3211264u     // mu partials: 8*64*8192 = 4194304
#define OFF_LVP   7405568u     // lv partials: 8*64*8192
#define OFF_CNT   11599872u    // atomic task counter (int)

// ---------------- mu tile body: NS samples, single k-pass, wv prefetch -------------
template <int NS>
__device__ __forceinline__ void mu_tile(const float* __restrict__ hmat,
                                        const float* __restrict__ wbase,
                                        float* __restrict__ mup_kc,
                                        const int* bo, int n, int k0, int o) {
    float4 acc[NS];
#pragma unroll
    for (int i = 0; i < NS; ++i) acc[i] = make_float4(0.f, 0.f, 0.f, 0.f);
    float4 wv[4];
#pragma unroll
    for (int kk = 0; kk < 4; ++kk)
        wv[kk] = *(const float4*)(wbase + (size_t)(k0 + kk) * OUTD + o);
    for (int k = k0; k < k0 + 128; k += 4) {
        float4 hv[NS];
#pragma unroll
        for (int i = 0; i < NS; ++i)
            hv[i] = *(const float4*)(hmat + bo[i] * HID + k);
        int kn = (k + 4 < k0 + 128) ? (k + 4) : k0;  // last-iter reload, harmless
        float4 wn[4];
#pragma unroll
        for (int kk = 0; kk < 4; ++kk)
            wn[kk] = *(const float4*)(wbase + (size_t)(kn + kk) * OUTD + o);
#pragma unroll
        for (int kk = 0; kk < 4; ++kk) {
            float4 w = wv[kk];
#pragma unroll
            for (int i = 0; i < NS; ++i) {
                float h = (kk == 0) ? hv[i].x : (kk == 1) ? hv[i].y
                        : (kk == 2) ? hv[i].z : hv[i].w;
                acc[i].x = fmaf(h, w.x, acc[i].x);
                acc[i].y = fmaf(h, w.y, acc[i].y);
                acc[i].z = fmaf(h, w.z, acc[i].z);
                acc[i].w = fmaf(h, w.w, acc[i].w);
            }
        }
#pragma unroll
        for (int kk = 0; kk < 4; ++kk) wv[kk] = wn[kk];
    }
#pragma unroll
    for (int i = 0; i < NS; ++i)
        if (i < n) *(float4*)(mup_kc + (size_t)bo[i] * OUTD + o) = acc[i];
}

__device__ __forceinline__ void mu_task(int t, const float* __restrict__ hbuf,
                                        const float* __restrict__ subj_w,
                                        const int* __restrict__ sid,
                                        float* __restrict__ mup, int tid) {
    int o  = (t >> 6) * 1024 + tid * 4;   // 8 ochunks
    int kc = (t >> 3) & 7;                // 8 kchunks
    int s  = t & 7;                       // 8 subjects
    int k0 = kc * 128;
    int lane = tid & 63;
    int mysid = sid[lane];
    unsigned long long m = __ballot(mysid == s);
    int ns = __popcll(m);
    if (ns == 0) return;
    const float* wbase = subj_w + (size_t)s * HID * OUTD;
    float* mup_kc = mup + (size_t)kc * BATCH * OUTD;
    unsigned long long mm = m;
    for (int base = 0; base < ns; base += 12) {
        int take = ns - base; if (take > 12) take = 12;
        int fb = (int)__builtin_ctzll(mm);
        int bo[12];
#pragma unroll
        for (int i = 0; i < 12; ++i) {
            bo[i] = (mm != 0ull) ? (int)__builtin_ctzll(mm) : fb;
            if (mm != 0ull) mm &= (mm - 1ull);
        }
        if (take <= 4)       mu_tile<4>(hbuf, wbase, mup_kc, bo, take, k0, o);
        else if (take <= 8)  mu_tile<8>(hbuf, wbase, mup_kc, bo, take, k0, o);
        else                 mu_tile<12>(hbuf, wbase, mup_kc, bo, take, k0, o);
    }
}

__device__ __forceinline__ void lv_task(int u, const float* __restrict__ hbuf,
                                        const float* __restrict__ lv_w,
                                        float* __restrict__ lvp, int tid) {
    int o  = (u & 15) * 512 + tid * 2;    // 16 ochunks
    int kc = (u >> 4) & 7;                // 8 kchunks
    int b0 = (u >> 7) * 32;               // 2 bgroups
    int k0 = kc * 128;
    float2 acc[32];
#pragma unroll
    for (int i = 0; i < 32; ++i) acc[i] = make_float2(0.f, 0.f);
    float2 wv0 = *(const float2*)(lv_w + (size_t)k0 * OUTD + o);
    float2 wv1 = *(const float2*)(lv_w + (size_t)(k0 + 1) * OUTD + o);
    for (int k = k0; k < k0 + 128; k += 2) {
        float2 hv[32];
#pragma unroll
        for (int i = 0; i < 32; ++i)
            hv[i] = *(const float2*)(hbuf + (b0 + i) * HID + k);
        int kn = (k + 2 < k0 + 128) ? (k + 2) : k0;
        float2 wn0 = *(const float2*)(lv_w + (size_t)kn * OUTD + o);
        float2 wn1 = *(const float2*)(lv_w + (size_t)(kn + 1) * OUTD + o);
#pragma unroll
        for (int i = 0; i < 32; ++i) {
            acc[i].x = fmaf(hv[i].x, wv0.x, acc[i].x);
            acc[i].y = fmaf(hv[i].x, wv0.y, acc[i].y);
            acc[i].x = fmaf(hv[i].y, wv1.x, acc[i].x);
            acc[i].y = fmaf(hv[i].y, wv1.y, acc[i].y);
        }
        wv0 = wn0; wv1 = wn1;
    }
#pragma unroll
    for (int i = 0; i < 32; ++i) {
        float* dst = lvp + ((size_t)kc * BATCH + b0 + i) * OUTD + o;
        dst[0] = acc[i].x; dst[1] = acc[i].y;
    }
}

// =============================== fused cooperative kernel ===========================
__global__ __launch_bounds__(256, 2) void k_fused(
        const float* __restrict__ ctx, const int* __restrict__ sid,
        const float* __restrict__ eps,
        const float* __restrict__ w1, const float* __restrict__ b1,
        const float* __restrict__ w2, const float* __restrict__ b2,
        const float* __restrict__ subj_w, const float* __restrict__ subj_b,
        const float* __restrict__ lv_w, const float* __restrict__ lv_b,
        float* __restrict__ out, float* __restrict__ ws) {
    cg::grid_group grid = cg::this_grid();
    float* pp   = ws + OFF_PP;
    float* p1   = ws + OFF_P1;
    float* p2   = ws + OFF_P2;
    float* hbuf = ws + OFF_H;
    float* mup  = ws + OFF_MUP;
    float* lvp  = ws + OFF_LVP;
    int* counter = (int*)(ws + OFF_CNT);
    const int bid = blockIdx.x;
    const int nb  = gridDim.x;
    const int tid = threadIdx.x;
    __shared__ float xs[32][72];
    __shared__ int task_s;

    // ---- P0: reset task counter + mean-pool partials (1024 tasks) ----
    if (bid == 0 && tid == 0) *counter = 0;
    for (int t = bid; t < 1024; t += nb) {
        int b = t >> 4, tc = t & 15;
        int hid = tid * 4;
        const float* base = ctx + ((size_t)b * TLEN + (size_t)tc * 32) * HID + hid;
        float4 acc = make_float4(0.f, 0.f, 0.f, 0.f);
#pragma unroll 8
        for (int tt = 0; tt < 32; ++tt) {
            float4 v = *(const float4*)(base + (size_t)tt * HID);
            acc.x += v.x; acc.y += v.y; acc.z += v.z; acc.w += v.w;
        }
        *(float4*)(pp + ((size_t)tc * BATCH + b) * HID + hid) = acc;
    }
    __threadfence();
    grid.sync();

    // ---- P1: mlp1 = pool-reduce (LDS tile) + GEMM1 partial (128 tasks) ----
    for (int t = bid; t < 128; t += nb) {
        int j  = (t & 3) * 256 + tid;
        int k0 = ((t >> 2) & 15) * 64;
        int b0 = (t >> 6) * 32;
        {
            int bb = tid >> 3;
            int kk8 = (tid & 7) * 8;
            float4 s0 = make_float4(0.f, 0.f, 0.f, 0.f);
            float4 s1 = make_float4(0.f, 0.f, 0.f, 0.f);
#pragma unroll
            for (int tc = 0; tc < 16; ++tc) {
                const float* bp = pp + (size_t)tc * 65536 + (b0 + bb) * HID + k0 + kk8;
                float4 v0 = *(const float4*)bp;
                float4 v1 = *(const float4*)(bp + 4);
                s0.x += v0.x; s0.y += v0.y; s0.z += v0.z; s0.w += v0.w;
                s1.x += v1.x; s1.y += v1.y; s1.z += v1.z; s1.w += v1.w;
            }
            const float inv = 1.0f / 512.0f;
            s0.x *= inv; s0.y *= inv; s0.z *= inv; s0.w *= inv;
            s1.x *= inv; s1.y *= inv; s1.z *= inv; s1.w *= inv;
            *(float4*)&xs[bb][kk8]     = s0;
            *(float4*)&xs[bb][kk8 + 4] = s1;
        }
        __syncthreads();
        float acc[32];
#pragma unroll
        for (int i = 0; i < 32; ++i) acc[i] = 0.f;
        for (int kk = 0; kk < 64; kk += 2) {
            float wa = w1[(size_t)(k0 + kk) * HID + j];
            float wb = w1[(size_t)(k0 + kk + 1) * HID + j];
#pragma unroll
            for (int i = 0; i < 32; ++i) {
                acc[i] = fmaf(xs[i][kk], wa, acc[i]);
                acc[i] = fmaf(xs[i][kk + 1], wb, acc[i]);
            }
        }
        float* dst = p1 + (size_t)((t >> 2) & 15) * 65536;
#pragma unroll
        for (int i = 0; i < 32; ++i) dst[(b0 + i) * HID + j] = acc[i];
        __syncthreads();
    }
    __threadfence();
    grid.sync();

    // ---- P2: mlp2 = reduce+bias+GELU (LDS tile) + GEMM2 partial (128 tasks) ----
    for (int t = bid; t < 128; t += nb) {
        int j  = (t & 3) * 256 + tid;
        int k0 = ((t >> 2) & 15) * 64;
        int b0 = (t >> 6) * 32;
        {
            int bb = tid >> 3;
            int kk8 = (tid & 7) * 8;
            float4 s0 = make_float4(0.f, 0.f, 0.f, 0.f);
            float4 s1 = make_float4(0.f, 0.f, 0.f, 0.f);
#pragma unroll
            for (int kc = 0; kc < 16; ++kc) {
                const float* bp = p1 + (size_t)kc * 65536 + (b0 + bb) * HID + k0 + kk8;
                float4 v0 = *(const float4*)bp;
                float4 v1 = *(const float4*)(bp + 4);
                s0.x += v0.x; s0.y += v0.y; s0.z += v0.z; s0.w += v0.w;
                s1.x += v1.x; s1.y += v1.y; s1.z += v1.z; s1.w += v1.w;
            }
            float4 bv0 = *(const float4*)(b1 + k0 + kk8);
            float4 bv1 = *(const float4*)(b1 + k0 + kk8 + 4);
            s0.x += bv0.x; s0.y += bv0.y; s0.z += bv0.z; s0.w += bv0.w;
            s1.x += bv1.x; s1.y += bv1.y; s1.z += bv1.z; s1.w += bv1.w;
            const float r = 0.70710678118654752f;
            xs[bb][kk8]     = 0.5f * s0.x * (1.0f + erff(s0.x * r));
            xs[bb][kk8 + 1] = 0.5f * s0.y * (1.0f + erff(s0.y * r));
            xs[bb][kk8 + 2] = 0.5f * s0.z * (1.0f + erff(s0.z * r));
            xs[bb][kk8 + 3] = 0.5f * s0.w * (1.0f + erff(s0.w * r));
            xs[bb][kk8 + 4] = 0.5f * s1.x * (1.0f + erff(s1.x * r));
            xs[bb][kk8 + 5] = 0.5f * s1.y * (1.0f + erff(s1.y * r));
            xs[bb][kk8 + 6] = 0.5f * s1.z * (1.0f + erff(s1.z * r));
            xs[bb][kk8 + 7] = 0.5f * s1.w * (1.0f + erff(s1.w * r));
        }
        __syncthreads();
        float acc[32];
#pragma unroll
        for (int i = 0; i < 32; ++i) acc[i] = 0.f;
        for (int kk = 0; kk < 64; kk += 2) {
            float wa = w2[(size_t)(k0 + kk) * HID + j];
            float wb = w2[(size_t)(k0 + kk + 1) * HID + j];
#pragma unroll
            for (int i = 0; i < 32; ++i) {
                acc[i] = fmaf(xs[i][kk], wa, acc[i]);
                acc[i] = fmaf(xs[i][kk + 1], wb, acc[i]);
            }
        }
        float* dst = p2 + (size_t)((t >> 2) & 15) * 65536;
#pragma unroll
        for (int i = 0; i < 32; ++i) dst[(b0 + i) * HID + j] = acc[i];
        __syncthreads();
    }
    __threadfence();
    grid.sync();

    // ---- P3: reduce p2 + bias -> hbuf (64 tasks) ----
    for (int t = bid; t < 64; t += nb) {
        int i = t * 1024 + tid * 4;
        float4 s = make_float4(0.f, 0.f, 0.f, 0.f);
#pragma unroll
        for (int kc = 0; kc < 16; ++kc) {
            float4 v = *(const float4*)(p2 + (size_t)kc * 65536 + i);
            s.x += v.x; s.y += v.y; s.z += v.z; s.w += v.w;
        }
        float4 bb = *(const float4*)(b2 + tid * 4);
        s.x += bb.x; s.y += bb.y; s.z += bb.z; s.w += bb.w;
        *(float4*)(hbuf + i) = s;
    }
    __threadfence();
    grid.sync();

    // ---- P4: mu (512 tasks) + lv (256 tasks), atomic work queue ----
    for (;;) {
        __syncthreads();
        if (tid == 0) task_s = atomicAdd(counter, 1);
        __syncthreads();
        int t = task_s;
        if (t >= 768) break;
        if (t < 512) mu_task(t, hbuf, subj_w, sid, mup, tid);
        else         lv_task(t - 512, hbuf, lv_w, lvp, tid);
    }
    __threadfence();
    grid.sync();

    // ---- P5: combine (512 tasks) ----
    for (int t = bid; t < 512; t += nb) {
        int idx = t * 1024 + tid * 4;
        int b = idx >> 13;
        int o = idx & (OUTD - 1);
        float4 m = make_float4(0.f, 0.f, 0.f, 0.f);
        float4 l = make_float4(0.f, 0.f, 0.f, 0.f);
#pragma unroll
        for (int kc = 0; kc < 8; ++kc) {
            float4 tv = *(const float4*)(mup + (size_t)kc * 524288 + idx);
            m.x += tv.x; m.y += tv.y; m.z += tv.z; m.w += tv.w;
            float4 u = *(const float4*)(lvp + (size_t)kc * 524288 + idx);
            l.x += u.x; l.y += u.y; l.z += u.z; l.w += u.w;
        }
        int s = sid[b];
        float4 sb = *(const float4*)(subj_b + s * OUTD + o);
        float4 lb = *(const float4*)(lv_b + o);
        m.x += sb.x; m.y += sb.y; m.z += sb.z; m.w += sb.w;
        l.x = fminf(fmaxf(l.x + lb.x, -10.f), 2.f);
        l.y = fminf(fmaxf(l.y + lb.y, -10.f), 2.f);
        l.z = fminf(fmaxf(l.z + lb.z, -10.f), 2.f);
        l.w = fminf(fmaxf(l.w + lb.w, -10.f), 2.f);
        float4 e = *(const float4*)(eps + idx);
        float4 x0;
        x0.x = m.x + e.x * __expf(0.5f * l.x);
        x0.y = m.y + e.y * __expf(0.5f * l.y);
        x0.z = m.z + e.z * __expf(0.5f * l.z);
        x0.w = m.w + e.w * __expf(0.5f * l.w);
        *(float4*)(out + idx) = x0;
        *(float4*)(out + 524288 + idx) = m;
        *(float4*)(out + 1048576 + idx) = l;
    }
}

// ====================== fallback path: round-4 proven kernels =======================
__global__ __launch_bounds__(256) void k_pool(const float* __restrict__ ctx,
                                              float* __restrict__ pp) {
    int b  = blockIdx.x;
    int tc = blockIdx.y;
    int hid = threadIdx.x * 4;
    const float* base = ctx + ((size_t)b * TLEN + (size_t)tc * 32) * HID + hid;
    float4 acc = make_float4(0.f, 0.f, 0.f, 0.f);
#pragma unroll 8
    for (int t = 0; t < 32; ++t) {
        float4 v = *(const float4*)(base + (size_t)t * HID);
        acc.x += v.x; acc.y += v.y; acc.z += v.z; acc.w += v.w;
    }
    *(float4*)(pp + ((size_t)tc * BATCH + b) * HID + hid) = acc;
}

__global__ __launch_bounds__(256) void k_mlp1(const float* __restrict__ pp,
                                              const float* __restrict__ w1,
                                              float* __restrict__ p1) {
    __shared__ float xs[32][34];
    int j  = blockIdx.x * 256 + threadIdx.x;
    int k0 = blockIdx.y * 32;
    int b0 = blockIdx.z * 32;
    {
        int bb = threadIdx.x >> 3;
        int kk = (threadIdx.x & 7) * 4;
        float4 s = make_float4(0.f, 0.f, 0.f, 0.f);
#pragma unroll
        for (int tc = 0; tc < 16; ++tc) {
            float4 v = *(const float4*)(pp + (size_t)tc * 65536 + (b0 + bb) * 1024 + k0 + kk);
            s.x += v.x; s.y += v.y; s.z += v.z; s.w += v.w;
        }
        const float inv = 1.0f / 512.0f;
        xs[bb][kk]     = s.x * inv;
        xs[bb][kk + 1] = s.y * inv;
        xs[bb][kk + 2] = s.z * inv;
        xs[bb][kk + 3] = s.w * inv;
    }
    __syncthreads();
    float acc[32];
#pragma unroll
    for (int i = 0; i < 32; ++i) acc[i] = 0.f;
    for (int kk = 0; kk < 32; kk += 2) {
        float wa = w1[(size_t)(k0 + kk) * HID + j];
        float wb = w1[(size_t)(k0 + kk + 1) * HID + j];
#pragma unroll
        for (int i = 0; i < 32; ++i) {
            acc[i] = fmaf(xs[i][kk], wa, acc[i]);
            acc[i] = fmaf(xs[i][kk + 1], wb, acc[i]);
        }
    }
    float* dst = p1 + (size_t)blockIdx.y * 65536;
#pragma unroll
    for (int i = 0; i < 32; ++i) dst[(b0 + i) * 1024 + j] = acc[i];
}

__global__ __launch_bounds__(256) void k_mlp2(const float* __restrict__ p1,
                                              const float* __restrict__ b1,
                                              const float* __restrict__ w2,
                                              float* __restrict__ p2) {
    __shared__ float xs[32][34];
    int j  = blockIdx.x * 256 + threadIdx.x;
    int k0 = blockIdx.y * 32;
    int b0 = blockIdx.z * 32;
    {
        int bb = threadIdx.x >> 3;
        int kk = (threadIdx.x & 7) * 4;
        float4 s = make_float4(0.f, 0.f, 0.f, 0.f);
#pragma unroll
        for (int kc = 0; kc < 32; ++kc) {
            float4 v = *(const float4*)(p1 + (size_t)kc * 65536 + (b0 + bb) * 1024 + k0 + kk);
            s.x += v.x; s.y += v.y; s.z += v.z; s.w += v.w;
        }
        float4 bbv = *(const float4*)(b1 + k0 + kk);
        s.x += bbv.x; s.y += bbv.y; s.z += bbv.z; s.w += bbv.w;
        const float r = 0.70710678118654752f;
        xs[bb][kk]     = 0.5f * s.x * (1.0f + erff(s.x * r));
        xs[bb][kk + 1] = 0.5f * s.y * (1.0f + erff(s.y * r));
        xs[bb][kk + 2] = 0.5f * s.z * (1.0f + erff(s.z * r));
        xs[bb][kk + 3] = 0.5f * s.w * (1.0f + erff(s.w * r));
    }
    __syncthreads();
    float acc[32];
#pragma unroll
    for (int i = 0; i < 32; ++i) acc[i] = 0.f;
    for (int kk = 0; kk < 32; kk += 2) {
        float wa = w2[(size_t)(k0 + kk) * HID + j];
        float wb = w2[(size_t)(k0 + kk + 1) * HID + j];
#pragma unroll
        for (int i = 0; i < 32; ++i) {
            acc[i] = fmaf(xs[i][kk], wa, acc[i]);
            acc[i] = fmaf(xs[i][kk + 1], wb, acc[i]);
        }
    }
    float* dst = p2 + (size_t)blockIdx.y * 65536;
#pragma unroll
    for (int i = 0; i < 32; ++i) dst[(b0 + i) * 1024 + j] = acc[i];
}

__global__ __launch_bounds__(256) void k_red_bias(const float* __restrict__ p,
                                                  const float* __restrict__ bias,
                                                  float* __restrict__ out,
                                                  int nchunk) {
    int i = (blockIdx.x * 256 + threadIdx.x) * 4;
    int j = i & (HID - 1);
    float4 s = make_float4(0.f, 0.f, 0.f, 0.f);
    for (int kc = 0; kc < nchunk; ++kc) {
        float4 v = *(const float4*)(p + (size_t)kc * 65536 + i);
        s.x += v.x; s.y += v.y; s.z += v.z; s.w += v.w;
    }
    float4 bb = *(const float4*)(bias + j);
    s.x += bb.x; s.y += bb.y; s.z += bb.z; s.w += bb.w;
    *(float4*)(out + i) = s;
}

__global__ __launch_bounds__(256) void k_mu(const float* __restrict__ hmat,
                                            const float* __restrict__ subj_w,
                                            const int* __restrict__ sid,
                                            float* __restrict__ mup) {
    int t = (blockIdx.z * 8 + blockIdx.y) * 8 + blockIdx.x;  // not used; keep shape
    (void)t;
    int tid = threadIdx.x;
    int task = ((blockIdx.x) << 6) + (blockIdx.y << 3) + blockIdx.z;
    mu_task(task, hmat, subj_w, sid, mup, tid);
}

__global__ __launch_bounds__(256) void k_lv(const float* __restrict__ hmat,
                                            const float* __restrict__ lv_w,
                                            float* __restrict__ lvp) {
    int u = (blockIdx.z << 7) + (blockIdx.y << 4) + blockIdx.x;
    lv_task(u, hmat, lv_w, lvp, threadIdx.x);
}

__global__ __launch_bounds__(256) void k_combine(const float* __restrict__ mup,
                                                 const float* __restrict__ lvp,
                                                 const float* __restrict__ eps,
                                                 const float* __restrict__ subj_b,
                                                 const float* __restrict__ lv_b,
                                                 const int* __restrict__ sid,
                                                 float* __restrict__ out) {
    int idx = (blockIdx.x * 256 + threadIdx.x) * 4;
    int b = idx >> 13;
    int o = idx & (OUTD - 1);
    float4 m = make_float4(0.f, 0.f, 0.f, 0.f);
    float4 l = make_float4(0.f, 0.f, 0.f, 0.f);
#pragma unroll
    for (int kc = 0; kc < 8; ++kc) {
        float4 t = *(const float4*)(mup + (size_t)kc * 524288 + idx);
        m.x += t.x; m.y += t.y; m.z += t.z; m.w += t.w;
        float4 u = *(const float4*)(lvp + (size_t)kc * 524288 + idx);
        l.x += u.x; l.y += u.y; l.z += u.z; l.w += u.w;
    }
    int s = sid[b];
    float4 sb = *(const float4*)(subj_b + s * OUTD + o);
    float4 lb = *(const float4*)(lv_b + o);
    m.x += sb.x; m.y += sb.y; m.z += sb.z; m.w += sb.w;
    l.x = fminf(fmaxf(l.x + lb.x, -10.f), 2.f);
    l.y = fminf(fmaxf(l.y + lb.y, -10.f), 2.f);
    l.z = fminf(fmaxf(l.z + lb.z, -10.f), 2.f);
    l.w = fminf(fmaxf(l.w + lb.w, -10.f), 2.f);
    float4 e = *(const float4*)(eps + idx);
    float4 x0;
    x0.x = m.x + e.x * __expf(0.5f * l.x);
    x0.y = m.y + e.y * __expf(0.5f * l.y);
    x0.z = m.z + e.z * __expf(0.5f * l.z);
    x0.w = m.w + e.w * __expf(0.5f * l.w);
    *(float4*)(out + idx) = x0;
    *(float4*)(out + 524288 + idx) = m;
    *(float4*)(out + 1048576 + idx) = l;
}

extern "C" void kernel_launch(void* const* d_in, const int* in_sizes, int n_in,
                              void* d_out, int out_size, void* d_ws, size_t ws_size,
                              hipStream_t stream) {
    const float* ctx    = (const float*)d_in[0];
    const int*   sid    = (const int*)  d_in[1];
    const float* eps    = (const float*)d_in[2];
    const float* w1     = (const float*)d_in[3];
    const float* b1     = (const float*)d_in[4];
    const float* w2     = (const float*)d_in[5];
    const float* b2     = (const float*)d_in[6];
    const float* subj_w = (const float*)d_in[7];
    const float* subj_b = (const float*)d_in[8];
    const float* lv_w   = (const float*)d_in[9];
    const float* lv_b   = (const float*)d_in[10];
    float* out = (float*)d_out;
    float* ws  = (float*)d_ws;

    float* pp   = ws + OFF_PP;
    float* p1   = ws + OFF_P1;
    float* p2   = ws + OFF_P2;
    float* hbuf = ws + OFF_H;
    float* mup  = ws + OFF_MUP;
    float* lvp  = ws + OFF_LVP;

    // ---- capture-safe queries: decide path deterministically every call ----
    int dev = 0;
    (void)hipGetDevice(&dev);
    int coop = 0;
    (void)hipDeviceGetAttribute(&coop, hipDeviceAttributeCooperativeLaunch, dev);
    int occ = 0;
    (void)hipOccupancyMaxActiveBlocksPerMultiprocessor(&occ, (const void*)k_fused, 256, 0);

    if (coop && occ >= 1) {
        int blocks = (occ >= 2) ? 512 : 256;
        void* args[] = {
            (void*)&ctx, (void*)&sid, (void*)&eps,
            (void*)&w1, (void*)&b1, (void*)&w2, (void*)&b2,
            (void*)&subj_w, (void*)&subj_b, (void*)&lv_w, (void*)&lv_b,
            (void*)&out, (void*)&ws
        };
        hipError_t err = hipLaunchCooperativeKernel((const void*)k_fused, dim3(blocks),
                                                    dim3(256), args, 0, stream);
        if (err == hipSuccess) return;
    }

    // ---- fallback: proven 7-kernel chain ----
    k_pool<<<dim3(BATCH, 16), 256, 0, stream>>>(ctx, pp);
    k_mlp1<<<dim3(4, 32, 2), 256, 0, stream>>>(pp, w1, p1);
    k_mlp2<<<dim3(4, 32, 2), 256, 0, stream>>>(p1, b1, w2, p2);
    k_red_bias<<<64, 256, 0, stream>>>(p2, b2, hbuf, 16);
    k_mu<<<dim3(8, 8, NSUBJ), 256, 0, stream>>>(hbuf, subj_w, sid, mup);
    k_lv<<<dim3(16, 8, 2), 256, 0, stream>>>(hbuf, lv_w, lvp);
    k_combine<<<512, 256, 0, stream>>>(mup, lvp, eps, subj_b, lv_b, sid, out);
}

// Round 7
// 207.813 us; speedup vs baseline: 2.6789x; 2.6789x over previous
//
#include <hip/hip_runtime.h>
#include <math.h>

#define HID   1024
#define OUTD  8192
#define NSUBJ 8
#define BATCH 64
#define TLEN  512

// ws layout (float offsets)
#define OFF_PP    0u           // pool partials: 32*64*1024 = 2097152
#define OFF_P1    2097152u     // mlp1 partials: 32*64*1024
#define OFF_P2    4194304u     // mlp2 partials: 32*64*1024
#define OFF_H     6291456u     // 64*1024
#define OFF_MUP   6356992u     // mu partials: 16*64*8192 = 8388608
#define OFF_LVP   14745600u    // lv partials: 8*64*8192 = 4194304

// ---------------- mean pool: partial sums over 16-t chunks (2048 blocks) ------------
__global__ __launch_bounds__(256) void k_pool(const float* __restrict__ ctx,
                                              float* __restrict__ pp) {
    int b  = blockIdx.x;   // 64
    int tc = blockIdx.y;   // 32
    int hid = threadIdx.x * 4;
    const float* base = ctx + ((size_t)b * TLEN + (size_t)tc * 16) * HID + hid;
    float4 acc = make_float4(0.f, 0.f, 0.f, 0.f);
#pragma unroll
    for (int t = 0; t < 16; ++t) {
        float4 v = *(const float4*)(base + (size_t)t * HID);
        acc.x += v.x; acc.y += v.y; acc.z += v.z; acc.w += v.w;
    }
    *(float4*)(pp + ((size_t)tc * BATCH + b) * HID + hid) = acc;
}

// -------- MLP layer 1: fused pool-reduce (LDS x-tile) + GEMM partial --------
__global__ __launch_bounds__(256) void k_mlp1(const float* __restrict__ pp,
                                              const float* __restrict__ w1,
                                              float* __restrict__ p1) {
    __shared__ float xs[32][34];
    int j  = blockIdx.x * 256 + threadIdx.x;  // 4 jchunks
    int k0 = blockIdx.y * 32;                 // 32 kchunks
    int b0 = blockIdx.z * 32;                 // 2 bgroups
    {
        int bb = threadIdx.x >> 3;
        int kk = (threadIdx.x & 7) * 4;
        float4 s = make_float4(0.f, 0.f, 0.f, 0.f);
#pragma unroll
        for (int tc = 0; tc < 32; ++tc) {
            float4 v = *(const float4*)(pp + (size_t)tc * 65536 + (b0 + bb) * 1024 + k0 + kk);
            s.x += v.x; s.y += v.y; s.z += v.z; s.w += v.w;
        }
        const float inv = 1.0f / 512.0f;
        xs[bb][kk]     = s.x * inv;
        xs[bb][kk + 1] = s.y * inv;
        xs[bb][kk + 2] = s.z * inv;
        xs[bb][kk + 3] = s.w * inv;
    }
    __syncthreads();
    float acc[32];
#pragma unroll
    for (int i = 0; i < 32; ++i) acc[i] = 0.f;
    for (int kk = 0; kk < 32; kk += 2) {
        float wa = w1[(size_t)(k0 + kk) * HID + j];
        float wb = w1[(size_t)(k0 + kk + 1) * HID + j];
#pragma unroll
        for (int i = 0; i < 32; ++i) {
            acc[i] = fmaf(xs[i][kk], wa, acc[i]);
            acc[i] = fmaf(xs[i][kk + 1], wb, acc[i]);
        }
    }
    float* dst = p1 + (size_t)blockIdx.y * 65536;
#pragma unroll
    for (int i = 0; i < 32; ++i) dst[(b0 + i) * 1024 + j] = acc[i];
}

// -------- MLP layer 2: fused reduce+bias+exact-GELU (LDS x-tile) + GEMM partial ----
__global__ __launch_bounds__(256) void k_mlp2(const float* __restrict__ p1,
                                              const float* __restrict__ b1,
                                              const float* __restrict__ w2,
                                              float* __restrict__ p2) {
    __shared__ float xs[32][34];
    int j  = blockIdx.x * 256 + threadIdx.x;
    int k0 = blockIdx.y * 32;
    int b0 = blockIdx.z * 32;
    {
        int bb = threadIdx.x >> 3;
        int kk = (threadIdx.x & 7) * 4;
        float4 s = make_float4(0.f, 0.f, 0.f, 0.f);
#pragma unroll
        for (int kc = 0; kc < 32; ++kc) {
            float4 v = *(const float4*)(p1 + (size_t)kc * 65536 + (b0 + bb) * 1024 + k0 + kk);
            s.x += v.x; s.y += v.y; s.z += v.z; s.w += v.w;
        }
        float4 bbv = *(const float4*)(b1 + k0 + kk);
        s.x += bbv.x; s.y += bbv.y; s.z += bbv.z; s.w += bbv.w;
        const float r = 0.70710678118654752f;
        xs[bb][kk]     = 0.5f * s.x * (1.0f + erff(s.x * r));
        xs[bb][kk + 1] = 0.5f * s.y * (1.0f + erff(s.y * r));
        xs[bb][kk + 2] = 0.5f * s.z * (1.0f + erff(s.z * r));
        xs[bb][kk + 3] = 0.5f * s.w * (1.0f + erff(s.w * r));
    }
    __syncthreads();
    float acc[32];
#pragma unroll
    for (int i = 0; i < 32; ++i) acc[i] = 0.f;
    for (int kk = 0; kk < 32; kk += 2) {
        float wa = w2[(size_t)(k0 + kk) * HID + j];
        float wb = w2[(size_t)(k0 + kk + 1) * HID + j];
#pragma unroll
        for (int i = 0; i < 32; ++i) {
            acc[i] = fmaf(xs[i][kk], wa, acc[i]);
            acc[i] = fmaf(xs[i][kk + 1], wb, acc[i]);
        }
    }
    float* dst = p2 + (size_t)blockIdx.y * 65536;
#pragma unroll
    for (int i = 0; i < 32; ++i) dst[(b0 + i) * 1024 + j] = acc[i];
}

// ---------------- reduce 32 partials + bias -> hbuf ----------------
__global__ __launch_bounds__(256) void k_red_bias(const float* __restrict__ p,
                                                  const float* __restrict__ bias,
                                                  float* __restrict__ out) {
    int i = (blockIdx.x * 256 + threadIdx.x) * 4;  // 64 blocks
    int j = i & (HID - 1);
    float4 s = make_float4(0.f, 0.f, 0.f, 0.f);
#pragma unroll
    for (int kc = 0; kc < 32; ++kc) {
        float4 v = *(const float4*)(p + (size_t)kc * 65536 + i);
        s.x += v.x; s.y += v.y; s.z += v.z; s.w += v.w;
    }
    float4 bb = *(const float4*)(bias + j);
    s.x += bb.x; s.y += bb.y; s.z += bb.z; s.w += bb.w;
    *(float4*)(out + i) = s;
}

// ---------------- mu tile body: NS samples, k-chunk 64, wv prefetch ----------------
template <int NS>
__device__ __forceinline__ void mu_tile(const float* __restrict__ hmat,
                                        const float* __restrict__ wbase,
                                        float* __restrict__ mup_kc,
                                        const int* bo, int n, int k0, int o) {
    float4 acc[NS];
#pragma unroll
    for (int i = 0; i < NS; ++i) acc[i] = make_float4(0.f, 0.f, 0.f, 0.f);
    float4 wv[4];
#pragma unroll
    for (int kk = 0; kk < 4; ++kk)
        wv[kk] = *(const float4*)(wbase + (size_t)(k0 + kk) * OUTD + o);
    for (int k = k0; k < k0 + 64; k += 4) {
        float4 hv[NS];
#pragma unroll
        for (int i = 0; i < NS; ++i)
            hv[i] = *(const float4*)(hmat + bo[i] * HID + k);
        int kn = (k + 4 < k0 + 64) ? (k + 4) : k0;  // last-iter reload, harmless
        float4 wn[4];
#pragma unroll
        for (int kk = 0; kk < 4; ++kk)
            wn[kk] = *(const float4*)(wbase + (size_t)(kn + kk) * OUTD + o);
#pragma unroll
        for (int kk = 0; kk < 4; ++kk) {
            float4 w = wv[kk];
#pragma unroll
            for (int i = 0; i < NS; ++i) {
                float h = (kk == 0) ? hv[i].x : (kk == 1) ? hv[i].y
                        : (kk == 2) ? hv[i].z : hv[i].w;
                acc[i].x = fmaf(h, w.x, acc[i].x);
                acc[i].y = fmaf(h, w.y, acc[i].y);
                acc[i].z = fmaf(h, w.z, acc[i].z);
                acc[i].w = fmaf(h, w.w, acc[i].w);
            }
        }
#pragma unroll
        for (int kk = 0; kk < 4; ++kk) wv[kk] = wn[kk];
    }
#pragma unroll
    for (int i = 0; i < NS; ++i)
        if (i < n) *(float4*)(mup_kc + (size_t)bo[i] * OUTD + o) = acc[i];
}

// ------- merged heads: blocks [0,1024) = mu (o8 x k16 x s8), [1024,1280) = lv ------
__global__ __launch_bounds__(256) void k_head(const float* __restrict__ hbuf,
                                              const float* __restrict__ subj_w,
                                              const float* __restrict__ lv_w,
                                              const int* __restrict__ sid,
                                              float* __restrict__ mup,
                                              float* __restrict__ lvp) {
    int blk = blockIdx.x;
    int tid = threadIdx.x;
    if (blk < 1024) {
        // ---- mu partial ----
        int o  = (blk >> 7) * 1024 + tid * 4;   // 8 ochunks
        int kc = (blk >> 3) & 15;               // 16 kchunks of 64
        int s  = blk & 7;                       // 8 subjects
        int k0 = kc * 64;
        int lane = tid & 63;
        int mysid = sid[lane];
        unsigned long long m = __ballot(mysid == s);
        int ns = __popcll(m);
        if (ns == 0) return;
        const float* wbase = subj_w + (size_t)s * HID * OUTD;
        float* mup_kc = mup + (size_t)kc * BATCH * OUTD;
        unsigned long long mm = m;
        for (int base = 0; base < ns; base += 12) {
            int take = ns - base; if (take > 12) take = 12;
            int fb = (int)__builtin_ctzll(mm);
            int bo[12];
#pragma unroll
            for (int i = 0; i < 12; ++i) {
                bo[i] = (mm != 0ull) ? (int)__builtin_ctzll(mm) : fb;
                if (mm != 0ull) mm &= (mm - 1ull);
            }
            if (take <= 4)       mu_tile<4>(hbuf, wbase, mup_kc, bo, take, k0, o);
            else if (take <= 8)  mu_tile<8>(hbuf, wbase, mup_kc, bo, take, k0, o);
            else                 mu_tile<12>(hbuf, wbase, mup_kc, bo, take, k0, o);
        }
    } else {
        // ---- log_var partial ----
        int u  = blk - 1024;                  // 256 tasks
        int o  = (u & 15) * 512 + tid * 2;    // 16 ochunks
        int kc = (u >> 4) & 7;                // 8 kchunks of 128
        int b0 = (u >> 7) * 32;               // 2 bgroups
        int k0 = kc * 128;
        float2 acc[32];
#pragma unroll
        for (int i = 0; i < 32; ++i) acc[i] = make_float2(0.f, 0.f);
        float2 wv0 = *(const float2*)(lv_w + (size_t)k0 * OUTD + o);
        float2 wv1 = *(const float2*)(lv_w + (size_t)(k0 + 1) * OUTD + o);
        for (int k = k0; k < k0 + 128; k += 2) {
            float2 hv[32];
#pragma unroll
            for (int i = 0; i < 32; ++i)
                hv[i] = *(const float2*)(hbuf + (b0 + i) * HID + k);
            int kn = (k + 2 < k0 + 128) ? (k + 2) : k0;
            float2 wn0 = *(const float2*)(lv_w + (size_t)kn * OUTD + o);
            float2 wn1 = *(const float2*)(lv_w + (size_t)(kn + 1) * OUTD + o);
#pragma unroll
            for (int i = 0; i < 32; ++i) {
                acc[i].x = fmaf(hv[i].x, wv0.x, acc[i].x);
                acc[i].y = fmaf(hv[i].x, wv0.y, acc[i].y);
                acc[i].x = fmaf(hv[i].y, wv1.x, acc[i].x);
                acc[i].y = fmaf(hv[i].y, wv1.y, acc[i].y);
            }
            wv0 = wn0; wv1 = wn1;
        }
#pragma unroll
        for (int i = 0; i < 32; ++i) {
            float* dst = lvp + ((size_t)kc * BATCH + b0 + i) * OUTD + o;
            dst[0] = acc[i].x; dst[1] = acc[i].y;
        }
    }
}

// ---------------- combine: biases, clip, sample; write x0|mu|log_var ----------------
__global__ __launch_bounds__(256) void k_combine(const float* __restrict__ mup,
                                                 const float* __restrict__ lvp,
                                                 const float* __restrict__ eps,
                                                 const float* __restrict__ subj_b,
                                                 const float* __restrict__ lv_b,
                                                 const int* __restrict__ sid,
                                                 float* __restrict__ out) {
    int idx = (blockIdx.x * 256 + threadIdx.x) * 4;  // over 524288
    int b = idx >> 13;
    int o = idx & (OUTD - 1);
    float4 m = make_float4(0.f, 0.f, 0.f, 0.f);
    float4 l = make_float4(0.f, 0.f, 0.f, 0.f);
#pragma unroll
    for (int kc = 0; kc < 16; ++kc) {
        float4 t = *(const float4*)(mup + (size_t)kc * 524288 + idx);
        m.x += t.x; m.y += t.y; m.z += t.z; m.w += t.w;
    }
#pragma unroll
    for (int kc = 0; kc < 8; ++kc) {
        float4 u = *(const float4*)(lvp + (size_t)kc * 524288 + idx);
        l.x += u.x; l.y += u.y; l.z += u.z; l.w += u.w;
    }
    int s = sid[b];
    float4 sb = *(const float4*)(subj_b + s * OUTD + o);
    float4 lb = *(const float4*)(lv_b + o);
    m.x += sb.x; m.y += sb.y; m.z += sb.z; m.w += sb.w;
    l.x = fminf(fmaxf(l.x + lb.x, -10.f), 2.f);
    l.y = fminf(fmaxf(l.y + lb.y, -10.f), 2.f);
    l.z = fminf(fmaxf(l.z + lb.z, -10.f), 2.f);
    l.w = fminf(fmaxf(l.w + lb.w, -10.f), 2.f);
    float4 e = *(const float4*)(eps + idx);
    float4 x0;
    x0.x = m.x + e.x * __expf(0.5f * l.x);
    x0.y = m.y + e.y * __expf(0.5f * l.y);
    x0.z = m.z + e.z * __expf(0.5f * l.z);
    x0.w = m.w + e.w * __expf(0.5f * l.w);
    *(float4*)(out + idx) = x0;
    *(float4*)(out + 524288 + idx) = m;
    *(float4*)(out + 1048576 + idx) = l;
}

extern "C" void kernel_launch(void* const* d_in, const int* in_sizes, int n_in,
                              void* d_out, int out_size, void* d_ws, size_t ws_size,
                              hipStream_t stream) {
    const float* ctx    = (const float*)d_in[0];
    const int*   sid    = (const int*)  d_in[1];
    const float* eps    = (const float*)d_in[2];
    const float* w1     = (const float*)d_in[3];
    const float* b1     = (const float*)d_in[4];
    const float* w2     = (const float*)d_in[5];
    const float* b2     = (const float*)d_in[6];
    const float* subj_w = (const float*)d_in[7];
    const float* subj_b = (const float*)d_in[8];
    const float* lv_w   = (const float*)d_in[9];
    const float* lv_b   = (const float*)d_in[10];
    float* out = (float*)d_out;

    float* ws   = (float*)d_ws;
    float* pp   = ws + OFF_PP;
    float* p1   = ws + OFF_P1;
    float* p2   = ws + OFF_P2;
    float* hbuf = ws + OFF_H;
    float* mup  = ws + OFF_MUP;
    float* lvp  = ws + OFF_LVP;

    k_pool<<<dim3(BATCH, 32), 256, 0, stream>>>(ctx, pp);
    k_mlp1<<<dim3(4, 32, 2), 256, 0, stream>>>(pp, w1, p1);
    k_mlp2<<<dim3(4, 32, 2), 256, 0, stream>>>(p1, b1, w2, p2);
    k_red_bias<<<64, 256, 0, stream>>>(p2, b2, hbuf);
    k_head<<<1280, 256, 0, stream>>>(hbuf, subj_w, lv_w, sid, mup, lvp);
    k_combine<<<512, 256, 0, stream>>>(mup, lvp, eps, subj_b, lv_b, sid, out);
}